// Round 7
// baseline (126.166 us; speedup 1.0000x reference)
//
#include <hip/hip_runtime.h>

// Periodic radius graph: out[i][j][k] = |(frac[j]-frac[i]+off[k]) @ cell|
// masked to (d2 > 1e-12 && d < 5.0), else 0. N=1024, 27 images.
// 113.2 MB fp32 output -> write floor ~18 us at 6.4 TB/s.
//
// R7 = R6 with the compile fix: __builtin_nontemporal_store needs a native
// clang vector type, not HIP's float4 struct -> use ext_vector_type(4).
//
// R6 theory (unchanged): R3-R5 plateau at kernel ~49 us (2.3 TB/s) regardless
// of VALU or barriers -> limiter is per-block store-drain convoy (vmcnt(0)
// before endpgm x 4096 short blocks) + cache install churn. Fix:
//  1. PERSISTENT blocks: 1024 blocks = 4/CU, GENS=4 tiles each, barrier-free
//     (wave-private LDS chunks); stores stay in flight across generations,
//     one endpgm drain per wave total.
//  2. Nontemporal streaming stores: bypass L2/L3 install churn from the
//     453 MB poison fill.
// Math identical to R4/R5: bit-exact vs numpy (absmax 0.0 in R1-R5).

#define NATOMS 1024
#define NIMG 27
#define THREADS 256
#define GENS 4
#define FLOATS_PER_WAVE (64 * NIMG)          // 1728 floats = 6912 B
#define VEC4_PER_WAVE (FLOATS_PER_WAVE / 4)  // 432
#define FLOATS_PER_BLOCK (THREADS * NIMG)    // 6912 floats = 27648 B LDS

typedef float f32x4 __attribute__((ext_vector_type(4)));

__global__ __launch_bounds__(256) void PeriodicRadiusGraph_kernel(
    const float* __restrict__ frac,   // [1024, 3]
    const float* __restrict__ cell,   // [3, 3]
    float* __restrict__ out)          // [1024, 1024, 27] flat
{
    __shared__ float tile[FLOATS_PER_BLOCK];

    const unsigned t = threadIdx.x;
    const unsigned w = t >> 6;        // wave 0..3
    const unsigned l = t & 63u;       // lane

    // cell rows (wave-uniform -> scalar loads), c[d][e]
    float c[3][3];
#pragma unroll
    for (int d = 0; d < 3; ++d)
#pragma unroll
        for (int e = 0; e < 3; ++e) c[d][e] = cell[3 * d + e];

    float* chunk = &tile[w * FLOATS_PER_WAVE];   // wave-private: no barriers
    float* row   = &chunk[l * NIMG];             // stride 27: 2-way bank = free

    for (int g = 0; g < GENS; ++g) {
        const unsigned T = blockIdx.x * GENS + (unsigned)g;  // tile 0..4095
        const unsigned q = T * THREADS + t;                  // pair i*1024+j
        const unsigned j = q & (NATOMS - 1u);
        const unsigned i = q >> 10;

        const float fix = frac[3u * i + 0u], fiy = frac[3u * i + 1u], fiz = frac[3u * i + 2u];
        const float fjx = frac[3u * j + 0u], fjy = frac[3u * j + 1u], fjz = frac[3u * j + 2u];

        const float df[3] = { fjx - fix, fjy - fiy, fjz - fiz };

        // fv[axis][s] = df + (s-1); same source exprs as bit-exact R1-R5.
        float fv[3][3];
#pragma unroll
        for (int a = 0; a < 3; ++a) {
            fv[a][0] = df[a] + (-1.0f);
            fv[a][1] = df[a] + 0.0f;
            fv[a][2] = df[a] + 1.0f;
        }

        // products p[axis][s][e] = fv[axis][s] * c[axis][e]  (27 muls)
        float p[3][3][3];
#pragma unroll
        for (int a = 0; a < 3; ++a)
#pragma unroll
            for (int s = 0; s < 3; ++s)
#pragma unroll
                for (int e = 0; e < 3; ++e) p[a][s][e] = fv[a][s] * c[a][e];

        // partial sums sxy[sx][sy][e] = p[0][sx][e] + p[1][sy][e]  (27 adds)
        float sxy[3][3][3];
#pragma unroll
        for (int sx = 0; sx < 3; ++sx)
#pragma unroll
            for (int sy = 0; sy < 3; ++sy)
#pragma unroll
                for (int e = 0; e < 3; ++e) sxy[sx][sy][e] = p[0][sx][e] + p[1][sy][e];

#pragma unroll
        for (int k = 0; k < NIMG; ++k) {
            const int sx = k / 9, sy = (k / 3) % 3, sz = k % 3;  // compile-time
            const float vx = sxy[sx][sy][0] + p[2][sz][0];
            const float vy = sxy[sx][sy][1] + p[2][sz][1];
            const float vz = sxy[sx][sy][2] + p[2][sz][2];
            const float d2 = vx * vx + vy * vy + vz * vz;
            const float d  = __builtin_amdgcn_sqrtf(d2);  // mask from d2: exact
            row[k] = (d2 > 1e-12f && d2 < 25.0f) ? d : 0.0f;
        }

        // Wave-private readback (lgkmcnt-ordered, in-order DS per wave) +
        // nontemporal streaming 16B stores. No vmcnt(0) until endpgm.
        const f32x4* chunk4 = (const f32x4*)chunk;
        f32x4* out4 = (f32x4*)(out + (size_t)T * FLOATS_PER_BLOCK
                                   + (size_t)w * FLOATS_PER_WAVE);
#pragma unroll
        for (int r = 0; r < 7; ++r) {
            const unsigned v = r * 64u + l;      // 6 full rounds + 48-lane tail
            if (v < VEC4_PER_WAVE) {
                __builtin_nontemporal_store(chunk4[v], &out4[v]);
            }
        }
    }
}

extern "C" void kernel_launch(void* const* d_in, const int* in_sizes, int n_in,
                              void* d_out, int out_size, void* d_ws, size_t ws_size,
                              hipStream_t stream) {
    const float* frac = (const float*)d_in[0];
    const float* cell = (const float*)d_in[1];
    float* out = (float*)d_out;

    const int grid = (NATOMS * NATOMS) / (THREADS * GENS);  // 1024 = 4/CU exact
    PeriodicRadiusGraph_kernel<<<grid, THREADS, 0, stream>>>(frac, cell, out);
}